// Round 2
// baseline (271.998 us; speedup 1.0000x reference)
//
#include <hip/hip_runtime.h>
#include <stdint.h>

typedef uint16_t u16;
typedef __attribute__((ext_vector_type(8))) _Float16 f16x8;
typedef __attribute__((ext_vector_type(4))) float f32x4;

#define NB 2
#define NT 2048
#define NC 1024
#define NH 16
#define ND 64
#define NM (NB*NT)   // 4096 rows of x
#define LOG2E 1.44269504088896340736f

__device__ __forceinline__ u16 f2h(float f) {
  _Float16 h = (_Float16)f;   // RNE
  return __builtin_bit_cast(u16, h);
}

// ---------------- f32 -> f16 convert, 4 elems/thread ----------------
__global__ __launch_bounds__(256) void cvt_kernel(const float* __restrict__ src,
                                                  u16* __restrict__ dst, int n4) {
  int i = blockIdx.x * 256 + threadIdx.x;
  if (i >= n4) return;
  float4 v = ((const float4*)src)[i];
  ushort4 o;
  o.x = f2h(v.x); o.y = f2h(v.y); o.z = f2h(v.z); o.w = f2h(v.w);
  ((ushort4*)dst)[i] = o;
}

// 4 weights -> one contiguous f16 region (Wq|Wk|Wv|Wproj)
__global__ __launch_bounds__(256) void cvtw_kernel(const float* __restrict__ w0,
                                                   const float* __restrict__ w1,
                                                   const float* __restrict__ w2,
                                                   const float* __restrict__ w3,
                                                   u16* __restrict__ dst) {
  int i = blockIdx.x * 256 + threadIdx.x;       // 0 .. 4*NC*NC/4
  int which = i >> 18;                          // NC*NC/4 = 262144
  const float* src = (which == 0) ? w0 : (which == 1) ? w1 : (which == 2) ? w2 : w3;
  int j = i & 262143;
  float4 v = ((const float4*)src)[j];
  ushort4 o;
  o.x = f2h(v.x); o.y = f2h(v.y); o.z = f2h(v.z); o.w = f2h(v.w);
  ((ushort4*)dst)[i] = o;
}

// ---------------- async global->LDS 16B ----------------
__device__ __forceinline__ void gload16(const void* g, void* l) {
  __builtin_amdgcn_global_load_lds(
      (const __attribute__((address_space(1))) void*)g,
      (__attribute__((address_space(3))) void*)l, 16, 0, 0);
}

// ---------------- GEMM, both operands k-major (C[m][n] = sum_k A[m][k]*B[n][k]) ---
// EPI 0: QKV epilogue (scatter q/k [BH][T][D] f16, v transposed [BH][D][T] f16,
//        q *= 0.125*log2(e) so attention works in exp2 domain)
// EPI 1: f32 row-major output
template<int EPI>
__global__ __launch_bounds__(256) void gemm_bt(const u16* __restrict__ A,
                                               const u16* __restrict__ Bw,
                                               int K, int N,
                                               u16* __restrict__ oq, u16* __restrict__ okk,
                                               u16* __restrict__ ovt,
                                               float* __restrict__ of) {
  __shared__ __align__(16) u16 Al[128*64];
  __shared__ __align__(16) u16 Bl[128*64];
  const int tid = threadIdx.x, lane = tid & 63, wid = tid >> 6;
  const int wm = wid >> 1, wn = wid & 1;
  const int m0 = blockIdx.y * 128, n0 = blockIdx.x * 128;
  const int srow = lane >> 3;          // row within an 8-row staging issue
  const int scol = (lane & 7) * 8;     // k-offset (elements) within row

  f32x4 acc[4][4] = {};

  for (int kt = 0; kt < K; kt += 64) {
    #pragma unroll
    for (int pp = 0; pp < 4; ++pp) {
      int r = wid*32 + pp*8;
      gload16(A  + (size_t)(m0 + r + srow)*K + kt + scol, &Al[r*64]);
      gload16(Bw + (size_t)(n0 + r + srow)*K + kt + scol, &Bl[r*64]);
    }
    __syncthreads();
    #pragma unroll
    for (int kk = 0; kk < 2; ++kk) {
      f16x8 af[4], bfr[4];
      #pragma unroll
      for (int mt = 0; mt < 4; ++mt)
        af[mt] = *(const f16x8*)&Al[(wm*64 + mt*16 + (lane&15))*64 + kk*32 + 8*(lane>>4)];
      #pragma unroll
      for (int nt = 0; nt < 4; ++nt)
        bfr[nt] = *(const f16x8*)&Bl[(wn*64 + nt*16 + (lane&15))*64 + kk*32 + 8*(lane>>4)];
      #pragma unroll
      for (int mt = 0; mt < 4; ++mt)
        #pragma unroll
        for (int nt = 0; nt < 4; ++nt)
          acc[mt][nt] = __builtin_amdgcn_mfma_f32_16x16x32_f16(af[mt], bfr[nt], acc[mt][nt], 0, 0, 0);
    }
    __syncthreads();
  }

  if (EPI == 0) {
    #pragma unroll
    for (int nt = 0; nt < 4; ++nt) {
      int n = n0 + wn*64 + nt*16 + (lane & 15);
      int sel = n >> 10;          // 0=q, 1=k, 2=v
      int nn = n & 1023;
      int h = nn >> 6, d = nn & 63;
      float scale = (sel == 0) ? 0.125f*LOG2E : 1.0f;
      #pragma unroll
      for (int mt = 0; mt < 4; ++mt) {
        #pragma unroll
        for (int r = 0; r < 4; ++r) {
          int m = m0 + wm*64 + mt*16 + (lane>>4)*4 + r;
          int b = m >> 11, t = m & (NT-1);
          u16 val = f2h(acc[mt][nt][r] * scale);
          int bh = b*NH + h;
          if (sel == 0)      oq [((size_t)bh*NT + t)*ND + d] = val;
          else if (sel == 1) okk[((size_t)bh*NT + t)*ND + d] = val;
          else               ovt[((size_t)bh*ND + d)*NT + t] = val;
        }
      }
    }
  } else {
    #pragma unroll
    for (int mt = 0; mt < 4; ++mt)
      #pragma unroll
      for (int r = 0; r < 4; ++r) {
        int m = m0 + wm*64 + mt*16 + (lane>>4)*4 + r;
        #pragma unroll
        for (int nt = 0; nt < 4; ++nt) {
          int n = n0 + wn*64 + nt*16 + (lane & 15);
          of[(size_t)m*N + n] = acc[mt][nt][r];
        }
      }
  }
}

// ---------------- flash attention, causal, pair-balanced + double-buffered ----
// grid: x = 16 q-tile PAIRS (j & 31-j -> 33 kv-iters per block, perfectly even),
//       y = B*H. 4 waves x 16 q-rows, KV tile = 64, K/V double-buffered in LDS.
// q pre-scaled by log2(e)/sqrt(D) -> softmax in exp2 domain.
__global__ __launch_bounds__(256) void attn_kernel(const u16* __restrict__ q,
                                                   const u16* __restrict__ k,
                                                   const u16* __restrict__ vt,
                                                   u16* __restrict__ y) {
  __shared__ __align__(16) u16 Kl[2][64*64];
  __shared__ __align__(16) u16 Vl[2][64*64];
  __shared__ __align__(16) u16 Pl[4*16*64];
  const int tid = threadIdx.x, lane = tid & 63, wid = tid >> 6;
  const int bh = blockIdx.y;
  const int pj = blockIdx.x;                 // pair index 0..15
  const u16* qp = q  + (size_t)bh*NT*ND;
  const u16* kp = k  + (size_t)bh*NT*ND;
  const u16* vp = vt + (size_t)bh*ND*NT;
  const int b = bh >> 4, h = bh & 15;
  const int srow = lane >> 3;
  const int scol8 = (lane & 7) ^ (srow & 7);  // pre-swizzled 16B-slot in global source
  u16* pl = &Pl[wid*1024];

  for (int half = 0; half < 2; ++half) {
    const int qtile = half ? (31 - pj) : pj;
    const int qs = qtile * 64;
    const int ntiles = qtile + 1;             // causal: kv tiles 0..qtile

    // Q A-fragments in registers for this q-tile
    f16x8 aq[2];
    {
      int t = qs + wid*16 + (lane & 15);
      #pragma unroll
      for (int c = 0; c < 2; ++c)
        aq[c] = *(const f16x8*)(qp + (size_t)t*ND + c*32 + 8*(lane>>4));
    }
    f32x4 accO[4] = {};
    float m_run[4], ssum[4];
    #pragma unroll
    for (int r = 0; r < 4; ++r) { m_run[r] = -1e30f; ssum[r] = 0.f; }

    __syncthreads();                          // LDS buffers free (prev half done)
    // prologue: stage kv tile 0 into buf 0
    #pragma unroll
    for (int pp = 0; pp < 2; ++pp) {
      int issue = wid*2 + pp;
      int row = issue*8 + srow;
      gload16(kp + (size_t)row*ND + scol8*8, &Kl[0][issue*512]);
      gload16(vp + (size_t)row*NT + scol8*8, &Vl[0][issue*512]);
    }

    int cur = 0;
    for (int kt = 0; kt < ntiles; ++kt) {
      const int kvs = kt*64;
      __syncthreads();                        // stage(kt) landed; prev compute done
      if (kt + 1 < ntiles) {                  // prefetch next tile under compute
        const int kvs2 = kvs + 64;
        #pragma unroll
        for (int pp = 0; pp < 2; ++pp) {
          int issue = wid*2 + pp;
          int row = issue*8 + srow;
          gload16(kp + (size_t)(kvs2 + row)*ND + scol8*8, &Kl[cur^1][issue*512]);
          gload16(vp + (size_t)row*NT + kvs2 + scol8*8, &Vl[cur^1][issue*512]);
        }
      }

      // S = Q K^T (scale+log2e folded into q)
      f32x4 sacc[4] = {};
      #pragma unroll
      for (int c = 0; c < 2; ++c) {
        #pragma unroll
        for (int nt = 0; nt < 4; ++nt) {
          int row = nt*16 + (lane & 15);
          int col = (c*32 + 8*(lane>>4)) ^ ((row & 7) << 3);
          f16x8 kb = *(const f16x8*)&Kl[cur][row*64 + col];
          sacc[nt] = __builtin_amdgcn_mfma_f32_16x16x32_f16(aq[c], kb, sacc[nt], 0, 0, 0);
        }
      }

      const int qrow_base = qs + wid*16 + (lane>>4)*4;
      if (kvs + 63 > qs + wid*16) {           // wave-uniform: only diagonal tile masks
        #pragma unroll
        for (int nt = 0; nt < 4; ++nt) {
          int kvg = kvs + nt*16 + (lane & 15);
          #pragma unroll
          for (int r = 0; r < 4; ++r)
            if (kvg > qrow_base + r) sacc[nt][r] = -1e30f;
        }
      }

      // row max (16-lane groups hold 16 kv cols each)
      float mloc[4];
      #pragma unroll
      for (int r = 0; r < 4; ++r) {
        float mv = fmaxf(fmaxf(sacc[0][r], sacc[1][r]), fmaxf(sacc[2][r], sacc[3][r]));
        #pragma unroll
        for (int off = 1; off < 16; off <<= 1)
          mv = fmaxf(mv, __shfl_xor(mv, off));
        mloc[r] = mv;
      }
      // defer-max: skip rescale when max grew by < 8 (P bounded by 2^8, f16-safe)
      bool ok = (mloc[0] <= m_run[0] + 8.f) && (mloc[1] <= m_run[1] + 8.f)
             && (mloc[2] <= m_run[2] + 8.f) && (mloc[3] <= m_run[3] + 8.f);
      const bool defer = __all(ok);

      float p[4][4];
      #pragma unroll
      for (int r = 0; r < 4; ++r) {
        float mnew = defer ? m_run[r] : fmaxf(m_run[r], mloc[r]);
        float ps = 0.f;
        #pragma unroll
        for (int nt = 0; nt < 4; ++nt) {
          float e = exp2f(sacc[nt][r] - mnew);
          p[nt][r] = e; ps += e;
        }
        #pragma unroll
        for (int off = 1; off < 16; off <<= 1)
          ps += __shfl_xor(ps, off);
        if (defer) {
          ssum[r] += ps;
        } else {
          float a = exp2f(m_run[r] - mnew);
          ssum[r] = ssum[r]*a + ps;
          m_run[r] = mnew;
          #pragma unroll
          for (int nt = 0; nt < 4; ++nt) accO[nt][r] *= a;
        }
      }

      // P -> LDS (f16, swizzled), per-wave private region
      #pragma unroll
      for (int r = 0; r < 4; ++r) {
        int row = (lane>>4)*4 + r;
        #pragma unroll
        for (int nt = 0; nt < 4; ++nt) {
          int col = (nt*16 + (lane & 15)) ^ ((row & 7) << 3);
          pl[row*64 + col] = f2h(p[nt][r]);
        }
      }

      // O += P V
      #pragma unroll
      for (int c = 0; c < 2; ++c) {
        int prow = lane & 15;
        int pcol = (c*32 + 8*(lane>>4)) ^ ((prow & 7) << 3);
        f16x8 pa = *(const f16x8*)&pl[prow*64 + pcol];
        #pragma unroll
        for (int nt = 0; nt < 4; ++nt) {
          int vrow = nt*16 + (lane & 15);
          int vcol = (c*32 + 8*(lane>>4)) ^ ((vrow & 7) << 3);
          f16x8 vb = *(const f16x8*)&Vl[cur][vrow*64 + vcol];
          accO[nt] = __builtin_amdgcn_mfma_f32_16x16x32_f16(pa, vb, accO[nt], 0, 0, 0);
        }
      }
      cur ^= 1;
    }

    // epilogue: y[b][t][h*64+d] = O / ssum, f16
    #pragma unroll
    for (int r = 0; r < 4; ++r) {
      int t = qs + wid*16 + (lane>>4)*4 + r;
      float inv = 1.0f / ssum[r];
      #pragma unroll
      for (int nt = 0; nt < 4; ++nt) {
        int d = nt*16 + (lane & 15);
        y[((size_t)(b*NT + t))*NC + h*ND + d] = f2h(accO[nt][r] * inv);
      }
    }
  }
}

// ---------------- launch ----------------
extern "C" void kernel_launch(void* const* d_in, const int* in_sizes, int n_in,
                              void* d_out, int out_size, void* d_ws, size_t ws_size,
                              hipStream_t stream) {
  const float* x  = (const float*)d_in[0];
  const float* Wq = (const float*)d_in[1];
  const float* Wk = (const float*)d_in[2];
  const float* Wv = (const float*)d_in[3];
  const float* Wp = (const float*)d_in[4];

  u16* xb   = (u16*)d_ws;                       // [4096][1024]
  u16* wqkv = xb   + (size_t)NM*NC;             // [3072][1024] (Wq|Wk|Wv rows)
  u16* wpj  = wqkv + (size_t)3*NC*NC;           // [1024][1024] (contiguous after wqkv)
  u16* qb   = wpj  + (size_t)NC*NC;             // [BH][T][D], pre-scaled log2e/8
  u16* kb   = qb   + (size_t)NM*NC;             // [BH][T][D]
  u16* vtb  = kb   + (size_t)NM*NC;             // [BH][D][T]
  u16* yb   = vtb  + (size_t)NM*NC;             // [4096][1024]
  size_t need = ((size_t)NM*NC*5 + (size_t)4*NC*NC) * sizeof(u16);
  if (ws_size < need) return;                   // fail loudly (output stays zero)

  cvt_kernel<<<NM*NC/4/256, 256, 0, stream>>>(x, xb, NM*NC/4);
  cvtw_kernel<<<4*NC*NC/4/256, 256, 0, stream>>>(Wq, Wk, Wv, Wp, wqkv);

  gemm_bt<0><<<dim3(3*NC/128, NM/128), 256, 0, stream>>>(xb, wqkv, NC, 3*NC,
                                                         qb, kb, vtb, nullptr);
  attn_kernel<<<dim3(16, NB*NH), 256, 0, stream>>>(qb, kb, vtb, yb);
  gemm_bt<1><<<dim3(NC/128, NM/128), 256, 0, stream>>>(yb, wpj, NC, NC,
                                                       nullptr, nullptr, nullptr,
                                                       (float*)d_out);
}

// Round 3
// 178.630 us; speedup vs baseline: 1.5227x; 1.5227x over previous
//
#include <hip/hip_runtime.h>
#include <stdint.h>

typedef uint16_t u16;
typedef uint32_t u32;
typedef __attribute__((ext_vector_type(8))) _Float16 f16x8;
typedef __attribute__((ext_vector_type(2))) _Float16 f16x2;
typedef __attribute__((ext_vector_type(4))) float f32x4;

#define NB 2
#define NT 2048
#define NC 1024
#define NH 16
#define ND 64
#define NM (NB*NT)   // 4096 rows of x
#define LOG2E 1.44269504088896340736f

__device__ __forceinline__ u16 f2h(float f) {
  _Float16 h = (_Float16)f;   // RNE
  return __builtin_bit_cast(u16, h);
}

// ---------------- f32 -> f16 convert, 4 elems/thread ----------------
__global__ __launch_bounds__(256) void cvt_kernel(const float* __restrict__ src,
                                                  u16* __restrict__ dst, int n4) {
  int i = blockIdx.x * 256 + threadIdx.x;
  if (i >= n4) return;
  float4 v = ((const float4*)src)[i];
  ushort4 o;
  o.x = f2h(v.x); o.y = f2h(v.y); o.z = f2h(v.z); o.w = f2h(v.w);
  ((ushort4*)dst)[i] = o;
}

// 4 weights -> one contiguous f16 region (Wq|Wk|Wv|Wproj)
__global__ __launch_bounds__(256) void cvtw_kernel(const float* __restrict__ w0,
                                                   const float* __restrict__ w1,
                                                   const float* __restrict__ w2,
                                                   const float* __restrict__ w3,
                                                   u16* __restrict__ dst) {
  int i = blockIdx.x * 256 + threadIdx.x;       // 0 .. 4*NC*NC/4
  int which = i >> 18;                          // NC*NC/4 = 262144
  const float* src = (which == 0) ? w0 : (which == 1) ? w1 : (which == 2) ? w2 : w3;
  int j = i & 262143;
  float4 v = ((const float4*)src)[j];
  ushort4 o;
  o.x = f2h(v.x); o.y = f2h(v.y); o.z = f2h(v.z); o.w = f2h(v.w);
  ((ushort4*)dst)[i] = o;
}

// ---------------- async global->LDS 16B ----------------
__device__ __forceinline__ void gload16(const void* g, void* l) {
  __builtin_amdgcn_global_load_lds(
      (const __attribute__((address_space(1))) void*)g,
      (__attribute__((address_space(3))) void*)l, 16, 0, 0);
}

// ---------------- GEMM, both operands k-major (C[m][n] = sum_k A[m][k]*B[n][k]) ---
// EPI 0: QKV epilogue (scatter q/k [BH][T][D] f16, v transposed [BH][D][T] f16,
//        q *= 0.125*log2(e) so attention works in exp2 domain)
// EPI 1: f32 row-major output
template<int EPI>
__global__ __launch_bounds__(256) void gemm_bt(const u16* __restrict__ A,
                                               const u16* __restrict__ Bw,
                                               int K, int N,
                                               u16* __restrict__ oq, u16* __restrict__ okk,
                                               u16* __restrict__ ovt,
                                               float* __restrict__ of) {
  __shared__ __align__(16) u16 Al[128*64];
  __shared__ __align__(16) u16 Bl[128*64];
  const int tid = threadIdx.x, lane = tid & 63, wid = tid >> 6;
  const int wm = wid >> 1, wn = wid & 1;
  const int m0 = blockIdx.y * 128, n0 = blockIdx.x * 128;
  const int srow = lane >> 3;          // row within an 8-row staging issue
  const int scol = (lane & 7) * 8;     // k-offset (elements) within row

  f32x4 acc[4][4] = {};

  for (int kt = 0; kt < K; kt += 64) {
    #pragma unroll
    for (int pp = 0; pp < 4; ++pp) {
      int r = wid*32 + pp*8;
      gload16(A  + (size_t)(m0 + r + srow)*K + kt + scol, &Al[r*64]);
      gload16(Bw + (size_t)(n0 + r + srow)*K + kt + scol, &Bl[r*64]);
    }
    __syncthreads();
    #pragma unroll
    for (int kk = 0; kk < 2; ++kk) {
      f16x8 af[4], bfr[4];
      #pragma unroll
      for (int mt = 0; mt < 4; ++mt)
        af[mt] = *(const f16x8*)&Al[(wm*64 + mt*16 + (lane&15))*64 + kk*32 + 8*(lane>>4)];
      #pragma unroll
      for (int nt = 0; nt < 4; ++nt)
        bfr[nt] = *(const f16x8*)&Bl[(wn*64 + nt*16 + (lane&15))*64 + kk*32 + 8*(lane>>4)];
      #pragma unroll
      for (int mt = 0; mt < 4; ++mt)
        #pragma unroll
        for (int nt = 0; nt < 4; ++nt)
          acc[mt][nt] = __builtin_amdgcn_mfma_f32_16x16x32_f16(af[mt], bfr[nt], acc[mt][nt], 0, 0, 0);
    }
    __syncthreads();
  }

  if (EPI == 0) {
    #pragma unroll
    for (int nt = 0; nt < 4; ++nt) {
      int n = n0 + wn*64 + nt*16 + (lane & 15);
      int sel = n >> 10;          // 0=q, 1=k, 2=v
      int nn = n & 1023;
      int h = nn >> 6, d = nn & 63;
      float scale = (sel == 0) ? 0.125f*LOG2E : 1.0f;
      #pragma unroll
      for (int mt = 0; mt < 4; ++mt) {
        #pragma unroll
        for (int r = 0; r < 4; ++r) {
          int m = m0 + wm*64 + mt*16 + (lane>>4)*4 + r;
          int b = m >> 11, t = m & (NT-1);
          u16 val = f2h(acc[mt][nt][r] * scale);
          int bh = b*NH + h;
          if (sel == 0)      oq [((size_t)bh*NT + t)*ND + d] = val;
          else if (sel == 1) okk[((size_t)bh*NT + t)*ND + d] = val;
          else               ovt[((size_t)bh*ND + d)*NT + t] = val;
        }
      }
    }
  } else {
    #pragma unroll
    for (int mt = 0; mt < 4; ++mt)
      #pragma unroll
      for (int r = 0; r < 4; ++r) {
        int m = m0 + wm*64 + mt*16 + (lane>>4)*4 + r;
        #pragma unroll
        for (int nt = 0; nt < 4; ++nt) {
          int n = n0 + wn*64 + nt*16 + (lane & 15);
          of[(size_t)m*N + n] = acc[mt][nt][r];
        }
      }
  }
}

// ---------------- flash attention, causal, swapped-QK^T lane-local softmax ----
// grid: x = 32 q-tiles, y = B*H (1024 blocks -> ~4 blocks/CU for TLP).
// 4 waves x 16 q-rows, KV tile = 64, single-buffered K/V in LDS.
// Swapped S^T = mfma(K, Q): lane owns q = lane&15, 16 kv values in regs ->
// softmax reduce = 15 in-lane ops + 2 shfl_xor (vs 32 shfls before).
// q pre-scaled by log2(e)/sqrt(D) -> softmax in exp2 domain.
__global__ __launch_bounds__(256) void attn_kernel(const u16* __restrict__ q,
                                                   const u16* __restrict__ k,
                                                   const u16* __restrict__ vt,
                                                   u16* __restrict__ y) {
  __shared__ __align__(16) u16 Kl[64*64];
  __shared__ __align__(16) u16 Vl[64*64];
  __shared__ __align__(16) u16 Pl[4*16*64];
  const int tid = threadIdx.x, lane = tid & 63, wid = tid >> 6;
  const int g = lane >> 4, qq = lane & 15;
  const int bh = blockIdx.y, qtile = blockIdx.x;
  const int qs = qtile * 64;
  const u16* qp = q  + (size_t)bh*NT*ND;
  const u16* kp = k  + (size_t)bh*NT*ND;
  const u16* vp = vt + (size_t)bh*ND*NT;
  const int b = bh >> 4, h = bh & 15;
  const int srow = lane >> 3;
  const int scol8 = (lane & 7) ^ (srow & 7);  // pre-swizzled 16B-slot in global source
  u16* pl = &Pl[wid*1024];
  u32* plw = (u32*)pl;

  // Q B-fragment in registers (col q = qs + wid*16 + qq)
  f16x8 aq[2];
  {
    int t = qs + wid*16 + qq;
    #pragma unroll
    for (int c = 0; c < 2; ++c)
      aq[c] = *(const f16x8*)(qp + (size_t)t*ND + c*32 + 8*g);
  }

  f32x4 accO[4] = {};               // O[q-local = g*4+r][d = nt*16+qq]
  float m_run = -1e30f, ssum = 0.f; // per-lane, q = qq (replicated across g)

  const int ntiles = qtile + 1;     // causal: kv tiles 0..qtile
  for (int kt = 0; kt < ntiles; ++kt) {
    const int kvs = kt*64;
    __syncthreads();                // all waves done reading prev K/V tile
    #pragma unroll
    for (int pp = 0; pp < 2; ++pp) {
      int issue = wid*2 + pp;
      int row = issue*8 + srow;
      gload16(kp + (size_t)(kvs + row)*ND + scol8*8, &Kl[issue*512]);
      gload16(vp + (size_t)row*NT + kvs + scol8*8, &Vl[issue*512]);
    }
    __syncthreads();                // vmcnt drained -> tile ready

    // S^T = K Q^T: rows kv (from K as A), cols q (from Q as B)
    f32x4 sacc[4] = {};             // sacc[nt][r]: kv = kvs+nt*16+g*4+r, q = qs+wid*16+qq
    __builtin_amdgcn_s_setprio(1);
    #pragma unroll
    for (int c = 0; c < 2; ++c) {
      #pragma unroll
      for (int nt = 0; nt < 4; ++nt) {
        int row = nt*16 + qq;
        int col = (c*32 + 8*g) ^ ((row & 7) << 3);
        f16x8 kb = *(const f16x8*)&Kl[row*64 + col];
        sacc[nt] = __builtin_amdgcn_mfma_f32_16x16x32_f16(kb, aq[c], sacc[nt], 0, 0, 0);
      }
    }
    __builtin_amdgcn_s_setprio(0);

    // causal mask (wave-uniform skip: only diagonal tiles mask)
    if (kvs + 63 > qs + wid*16) {
      int qg = qs + wid*16 + qq;
      #pragma unroll
      for (int nt = 0; nt < 4; ++nt)
        #pragma unroll
        for (int r = 0; r < 4; ++r)
          if (kvs + nt*16 + g*4 + r > qg) sacc[nt][r] = -1e30f;
    }

    // lane-local softmax: max/sum over 16 in-lane + 2 shfl (xor 16, 32)
    float mloc = sacc[0][0];
    #pragma unroll
    for (int nt = 0; nt < 4; ++nt)
      #pragma unroll
      for (int r = 0; r < 4; ++r) mloc = fmaxf(mloc, sacc[nt][r]);
    mloc = fmaxf(mloc, __shfl_xor(mloc, 16));
    mloc = fmaxf(mloc, __shfl_xor(mloc, 32));

    const bool defer = __all(mloc <= m_run + 8.f);   // P bounded by 2^8, f16-safe
    float mnew = defer ? m_run : fmaxf(m_run, mloc);

    float p[4][4];
    float ps = 0.f;
    #pragma unroll
    for (int nt = 0; nt < 4; ++nt)
      #pragma unroll
      for (int r = 0; r < 4; ++r) {
        float e = exp2f(sacc[nt][r] - mnew);
        p[nt][r] = e; ps += e;
      }
    ps += __shfl_xor(ps, 16);
    ps += __shfl_xor(ps, 32);

    if (defer) {
      ssum += ps;
    } else {
      float a = exp2f(m_run - mnew);
      ssum = ssum*a + ps;
      m_run = mnew;
      #pragma unroll
      for (int r = 0; r < 4; ++r) {       // broadcast alpha[q=g*4+r] from lane (lane&48)+g*4+r
        float ar = __shfl(a, (lane & 48) + g*4 + r);
        #pragma unroll
        for (int nt = 0; nt < 4; ++nt) accO[nt][r] *= ar;
      }
    }

    // pack P (f16 pairs) -> per-wave LDS [q][kv], 16B-slot XOR swizzle
    #pragma unroll
    for (int nt = 0; nt < 4; ++nt)
      #pragma unroll
      for (int t2 = 0; t2 < 2; ++t2) {
        u32 pk = __builtin_bit_cast(u32,
                   __builtin_amdgcn_cvt_pkrtz(p[nt][2*t2], p[nt][2*t2+1]));
        int kv = nt*16 + g*4 + 2*t2;
        plw[(qq*64 + (kv ^ ((qq & 7) << 3))) >> 1] = pk;
      }

    // O += P V : A = P[q][kv] (LDS, wave-local), B = V^T[d][kv]
    __builtin_amdgcn_s_setprio(1);
    #pragma unroll
    for (int c = 0; c < 2; ++c) {
      f16x8 pa = *(const f16x8*)&pl[qq*64 + ((c*32 + 8*g) ^ ((qq & 7) << 3))];
      #pragma unroll
      for (int nt = 0; nt < 4; ++nt) {
        int vrow = nt*16 + qq;
        int vcol = (c*32 + 8*g) ^ ((vrow & 7) << 3);
        f16x8 vb = *(const f16x8*)&Vl[vrow*64 + vcol];
        accO[nt] = __builtin_amdgcn_mfma_f32_16x16x32_f16(pa, vb, accO[nt], 0, 0, 0);
      }
    }
    __builtin_amdgcn_s_setprio(0);
  }

  // epilogue: y[b][t][h*64+d] = O / ssum, f16
  float inv = 1.0f / ssum;
  #pragma unroll
  for (int r = 0; r < 4; ++r) {
    float invr = __shfl(inv, (lane & 48) + g*4 + r);
    int t = qs + wid*16 + g*4 + r;
    #pragma unroll
    for (int nt = 0; nt < 4; ++nt) {
      int d = nt*16 + qq;
      y[((size_t)(b*NT + t))*NC + h*ND + d] = f2h(accO[nt][r] * invr);
    }
  }
}

// ---------------- launch ----------------
extern "C" void kernel_launch(void* const* d_in, const int* in_sizes, int n_in,
                              void* d_out, int out_size, void* d_ws, size_t ws_size,
                              hipStream_t stream) {
  const float* x  = (const float*)d_in[0];
  const float* Wq = (const float*)d_in[1];
  const float* Wk = (const float*)d_in[2];
  const float* Wv = (const float*)d_in[3];
  const float* Wp = (const float*)d_in[4];

  u16* xb   = (u16*)d_ws;                       // [4096][1024]
  u16* wqkv = xb   + (size_t)NM*NC;             // [3072][1024] (Wq|Wk|Wv rows)
  u16* wpj  = wqkv + (size_t)3*NC*NC;           // [1024][1024] (contiguous after wqkv)
  u16* qb   = wpj  + (size_t)NC*NC;             // [BH][T][D], pre-scaled log2e/8
  u16* kb   = qb   + (size_t)NM*NC;             // [BH][T][D]
  u16* vtb  = kb   + (size_t)NM*NC;             // [BH][D][T]
  u16* yb   = vtb  + (size_t)NM*NC;             // [4096][1024]
  size_t need = ((size_t)NM*NC*5 + (size_t)4*NC*NC) * sizeof(u16);
  if (ws_size < need) return;                   // fail loudly (output stays zero)

  cvt_kernel<<<NM*NC/4/256, 256, 0, stream>>>(x, xb, NM*NC/4);
  cvtw_kernel<<<4*NC*NC/4/256, 256, 0, stream>>>(Wq, Wk, Wv, Wp, wqkv);

  gemm_bt<0><<<dim3(3*NC/128, NM/128), 256, 0, stream>>>(xb, wqkv, NC, 3*NC,
                                                         qb, kb, vtb, nullptr);
  attn_kernel<<<dim3(32, NB*NH), 256, 0, stream>>>(qb, kb, vtb, yb);
  gemm_bt<1><<<dim3(NC/128, NM/128), 256, 0, stream>>>(yb, wpj, NC, NC,
                                                       nullptr, nullptr, nullptr,
                                                       (float*)d_out);
}

// Round 4
// 178.040 us; speedup vs baseline: 1.5277x; 1.0033x over previous
//
#include <hip/hip_runtime.h>
#include <stdint.h>

typedef uint16_t u16;
typedef uint32_t u32;
typedef __attribute__((ext_vector_type(8))) _Float16 f16x8;
typedef __attribute__((ext_vector_type(2))) _Float16 f16x2;
typedef __attribute__((ext_vector_type(4))) float f32x4;

#define NB 2
#define NT 2048
#define NC 1024
#define NH 16
#define ND 64
#define NM (NB*NT)   // 4096 rows of x
#define LOG2E 1.44269504088896340736f

__device__ __forceinline__ u16 f2h(float f) {
  _Float16 h = (_Float16)f;   // RNE
  return __builtin_bit_cast(u16, h);
}

// ---------------- f32 -> f16 convert, 4 elems/thread ----------------
__global__ __launch_bounds__(256) void cvt_kernel(const float* __restrict__ src,
                                                  u16* __restrict__ dst, int n4) {
  int i = blockIdx.x * 256 + threadIdx.x;
  if (i >= n4) return;
  float4 v = ((const float4*)src)[i];
  ushort4 o;
  o.x = f2h(v.x); o.y = f2h(v.y); o.z = f2h(v.z); o.w = f2h(v.w);
  ((ushort4*)dst)[i] = o;
}

// 4 weights -> one contiguous f16 region (Wq|Wk|Wv|Wproj)
__global__ __launch_bounds__(256) void cvtw_kernel(const float* __restrict__ w0,
                                                   const float* __restrict__ w1,
                                                   const float* __restrict__ w2,
                                                   const float* __restrict__ w3,
                                                   u16* __restrict__ dst) {
  int i = blockIdx.x * 256 + threadIdx.x;       // 0 .. 4*NC*NC/4
  int which = i >> 18;                          // NC*NC/4 = 262144
  const float* src = (which == 0) ? w0 : (which == 1) ? w1 : (which == 2) ? w2 : w3;
  int j = i & 262143;
  float4 v = ((const float4*)src)[j];
  ushort4 o;
  o.x = f2h(v.x); o.y = f2h(v.y); o.z = f2h(v.z); o.w = f2h(v.w);
  ((ushort4*)dst)[i] = o;
}

// ---------------- async global->LDS 16B ----------------
__device__ __forceinline__ void gload16(const void* g, void* l) {
  __builtin_amdgcn_global_load_lds(
      (const __attribute__((address_space(1))) void*)g,
      (__attribute__((address_space(3))) void*)l, 16, 0, 0);
}

// ---------------- GEMM, both operands k-major (C[m][n] = sum_k A[m][k]*B[n][k]) ---
// EPI 0: QKV epilogue (scatter q/k [BH][T][D] f16, v transposed [BH][D][T] f16,
//        q *= 0.125*log2(e) so attention works in exp2 domain)
// EPI 1: f32 row-major output
template<int EPI>
__global__ __launch_bounds__(256) void gemm_bt(const u16* __restrict__ A,
                                               const u16* __restrict__ Bw,
                                               int K, int N,
                                               u16* __restrict__ oq, u16* __restrict__ okk,
                                               u16* __restrict__ ovt,
                                               float* __restrict__ of) {
  __shared__ __align__(16) u16 Al[128*64];
  __shared__ __align__(16) u16 Bl[128*64];
  const int tid = threadIdx.x, lane = tid & 63, wid = tid >> 6;
  const int wm = wid >> 1, wn = wid & 1;
  const int m0 = blockIdx.y * 128, n0 = blockIdx.x * 128;
  const int srow = lane >> 3;          // row within an 8-row staging issue
  const int scol = (lane & 7) * 8;     // k-offset (elements) within row

  f32x4 acc[4][4] = {};

  for (int kt = 0; kt < K; kt += 64) {
    #pragma unroll
    for (int pp = 0; pp < 4; ++pp) {
      int r = wid*32 + pp*8;
      gload16(A  + (size_t)(m0 + r + srow)*K + kt + scol, &Al[r*64]);
      gload16(Bw + (size_t)(n0 + r + srow)*K + kt + scol, &Bl[r*64]);
    }
    __syncthreads();
    #pragma unroll
    for (int kk = 0; kk < 2; ++kk) {
      f16x8 af[4], bfr[4];
      #pragma unroll
      for (int mt = 0; mt < 4; ++mt)
        af[mt] = *(const f16x8*)&Al[(wm*64 + mt*16 + (lane&15))*64 + kk*32 + 8*(lane>>4)];
      #pragma unroll
      for (int nt = 0; nt < 4; ++nt)
        bfr[nt] = *(const f16x8*)&Bl[(wn*64 + nt*16 + (lane&15))*64 + kk*32 + 8*(lane>>4)];
      #pragma unroll
      for (int mt = 0; mt < 4; ++mt)
        #pragma unroll
        for (int nt = 0; nt < 4; ++nt)
          acc[mt][nt] = __builtin_amdgcn_mfma_f32_16x16x32_f16(af[mt], bfr[nt], acc[mt][nt], 0, 0, 0);
    }
    __syncthreads();
  }

  if (EPI == 0) {
    #pragma unroll
    for (int nt = 0; nt < 4; ++nt) {
      int n = n0 + wn*64 + nt*16 + (lane & 15);
      int sel = n >> 10;          // 0=q, 1=k, 2=v
      int nn = n & 1023;
      int h = nn >> 6, d = nn & 63;
      float scale = (sel == 0) ? 0.125f*LOG2E : 1.0f;
      #pragma unroll
      for (int mt = 0; mt < 4; ++mt) {
        #pragma unroll
        for (int r = 0; r < 4; ++r) {
          int m = m0 + wm*64 + mt*16 + (lane>>4)*4 + r;
          int b = m >> 11, t = m & (NT-1);
          u16 val = f2h(acc[mt][nt][r] * scale);
          int bh = b*NH + h;
          if (sel == 0)      oq [((size_t)bh*NT + t)*ND + d] = val;
          else if (sel == 1) okk[((size_t)bh*NT + t)*ND + d] = val;
          else               ovt[((size_t)bh*ND + d)*NT + t] = val;
        }
      }
    }
  } else {
    #pragma unroll
    for (int mt = 0; mt < 4; ++mt)
      #pragma unroll
      for (int r = 0; r < 4; ++r) {
        int m = m0 + wm*64 + mt*16 + (lane>>4)*4 + r;
        #pragma unroll
        for (int nt = 0; nt < 4; ++nt) {
          int n = n0 + wn*64 + nt*16 + (lane & 15);
          of[(size_t)m*N + n] = acc[mt][nt][r];
        }
      }
  }
}

// ---------------- flash attention, causal, swapped-QK^T lane-local softmax ----
// grid: x = 32 q-tiles, y = B*H (1024 blocks -> ~4 blocks/CU for TLP).
// 4 waves x 16 q-rows, KV tile = 64, single-buffered K/V in LDS.
// Swapped S^T = mfma(K, Q): lane owns q = lane&15, 16 kv values in regs ->
// softmax reduce = 15 in-lane ops + 2 shfl_xor (vs 32 shfls before).
// q pre-scaled by log2(e)/sqrt(D) -> softmax in exp2 domain.
__global__ __launch_bounds__(256) void attn_kernel(const u16* __restrict__ q,
                                                   const u16* __restrict__ k,
                                                   const u16* __restrict__ vt,
                                                   u16* __restrict__ y) {
  __shared__ __align__(16) u16 Kl[64*64];
  __shared__ __align__(16) u16 Vl[64*64];
  __shared__ __align__(16) u16 Pl[4*16*64];
  const int tid = threadIdx.x, lane = tid & 63, wid = tid >> 6;
  const int g = lane >> 4, qq = lane & 15;
  const int bh = blockIdx.y, qtile = blockIdx.x;
  const int qs = qtile * 64;
  const u16* qp = q  + (size_t)bh*NT*ND;
  const u16* kp = k  + (size_t)bh*NT*ND;
  const u16* vp = vt + (size_t)bh*ND*NT;
  const int b = bh >> 4, h = bh & 15;
  const int srow = lane >> 3;
  const int scol8 = (lane & 7) ^ (srow & 7);  // pre-swizzled 16B-slot in global source
  u16* pl = &Pl[wid*1024];
  u32* plw = (u32*)pl;

  // Q B-fragment in registers (col q = qs + wid*16 + qq)
  f16x8 aq[2];
  {
    int t = qs + wid*16 + qq;
    #pragma unroll
    for (int c = 0; c < 2; ++c)
      aq[c] = *(const f16x8*)(qp + (size_t)t*ND + c*32 + 8*g);
  }

  f32x4 accO[4] = {};               // O[q-local = g*4+r][d = nt*16+qq]
  float m_run = -1e30f, ssum = 0.f; // per-lane, q = qq (replicated across g)

  const int ntiles = qtile + 1;     // causal: kv tiles 0..qtile
  for (int kt = 0; kt < ntiles; ++kt) {
    const int kvs = kt*64;
    __syncthreads();                // all waves done reading prev K/V tile
    #pragma unroll
    for (int pp = 0; pp < 2; ++pp) {
      int issue = wid*2 + pp;
      int row = issue*8 + srow;
      gload16(kp + (size_t)(kvs + row)*ND + scol8*8, &Kl[issue*512]);
      gload16(vp + (size_t)row*NT + kvs + scol8*8, &Vl[issue*512]);
    }
    __syncthreads();                // vmcnt drained -> tile ready

    // S^T = K Q^T: rows kv (from K as A), cols q (from Q as B)
    f32x4 sacc[4] = {};             // sacc[nt][r]: kv = kvs+nt*16+g*4+r, q = qs+wid*16+qq
    __builtin_amdgcn_s_setprio(1);
    #pragma unroll
    for (int c = 0; c < 2; ++c) {
      #pragma unroll
      for (int nt = 0; nt < 4; ++nt) {
        int row = nt*16 + qq;
        int col = (c*32 + 8*g) ^ ((row & 7) << 3);
        f16x8 kb = *(const f16x8*)&Kl[row*64 + col];
        sacc[nt] = __builtin_amdgcn_mfma_f32_16x16x32_f16(kb, aq[c], sacc[nt], 0, 0, 0);
      }
    }
    __builtin_amdgcn_s_setprio(0);

    // causal mask (wave-uniform skip: only diagonal tiles mask)
    if (kvs + 63 > qs + wid*16) {
      int qg = qs + wid*16 + qq;
      #pragma unroll
      for (int nt = 0; nt < 4; ++nt)
        #pragma unroll
        for (int r = 0; r < 4; ++r)
          if (kvs + nt*16 + g*4 + r > qg) sacc[nt][r] = -1e30f;
    }

    // lane-local softmax: max/sum over 16 in-lane + 2 shfl (xor 16, 32)
    float mloc = sacc[0][0];
    #pragma unroll
    for (int nt = 0; nt < 4; ++nt)
      #pragma unroll
      for (int r = 0; r < 4; ++r) mloc = fmaxf(mloc, sacc[nt][r]);
    mloc = fmaxf(mloc, __shfl_xor(mloc, 16));
    mloc = fmaxf(mloc, __shfl_xor(mloc, 32));

    const bool defer = __all(mloc <= m_run + 8.f);   // P bounded by 2^8, f16-safe
    float mnew = defer ? m_run : fmaxf(m_run, mloc);

    float p[4][4];
    float ps = 0.f;
    #pragma unroll
    for (int nt = 0; nt < 4; ++nt)
      #pragma unroll
      for (int r = 0; r < 4; ++r) {
        float e = exp2f(sacc[nt][r] - mnew);
        p[nt][r] = e; ps += e;
      }
    ps += __shfl_xor(ps, 16);
    ps += __shfl_xor(ps, 32);

    if (defer) {
      ssum += ps;
    } else {
      float a = exp2f(m_run - mnew);
      ssum = ssum*a + ps;
      m_run = mnew;
      #pragma unroll
      for (int r = 0; r < 4; ++r) {       // broadcast alpha[q=g*4+r] from lane (lane&48)+g*4+r
        float ar = __shfl(a, (lane & 48) + g*4 + r);
        #pragma unroll
        for (int nt = 0; nt < 4; ++nt) accO[nt][r] *= ar;
      }
    }

    // pack P (f16 pairs) -> per-wave LDS [q][kv], 16B-slot XOR swizzle
    #pragma unroll
    for (int nt = 0; nt < 4; ++nt)
      #pragma unroll
      for (int t2 = 0; t2 < 2; ++t2) {
        u32 pk = __builtin_bit_cast(u32,
                   __builtin_amdgcn_cvt_pkrtz(p[nt][2*t2], p[nt][2*t2+1]));
        int kv = nt*16 + g*4 + 2*t2;
        plw[(qq*64 + (kv ^ ((qq & 7) << 3))) >> 1] = pk;
      }

    // O += P V : A = P[q][kv] (LDS, wave-local), B = V^T[d][kv]
    __builtin_amdgcn_s_setprio(1);
    #pragma unroll
    for (int c = 0; c < 2; ++c) {
      f16x8 pa = *(const f16x8*)&pl[qq*64 + ((c*32 + 8*g) ^ ((qq & 7) << 3))];
      #pragma unroll
      for (int nt = 0; nt < 4; ++nt) {
        int vrow = nt*16 + qq;
        int vcol = (c*32 + 8*g) ^ ((vrow & 7) << 3);
        f16x8 vb = *(const f16x8*)&Vl[vrow*64 + vcol];
        accO[nt] = __builtin_amdgcn_mfma_f32_16x16x32_f16(pa, vb, accO[nt], 0, 0, 0);
      }
    }
    __builtin_amdgcn_s_setprio(0);
  }

  // epilogue: y[b][t][h*64+d] = O / ssum, f16
  float inv = 1.0f / ssum;
  #pragma unroll
  for (int r = 0; r < 4; ++r) {
    float invr = __shfl(inv, (lane & 48) + g*4 + r);
    int t = qs + wid*16 + g*4 + r;
    #pragma unroll
    for (int nt = 0; nt < 4; ++nt) {
      int d = nt*16 + qq;
      y[((size_t)(b*NT + t))*NC + h*ND + d] = f2h(accO[nt][r] * invr);
    }
  }
}

// ---------------- launch ----------------
extern "C" void kernel_launch(void* const* d_in, const int* in_sizes, int n_in,
                              void* d_out, int out_size, void* d_ws, size_t ws_size,
                              hipStream_t stream) {
  const float* x  = (const float*)d_in[0];
  const float* Wq = (const float*)d_in[1];
  const float* Wk = (const float*)d_in[2];
  const float* Wv = (const float*)d_in[3];
  const float* Wp = (const float*)d_in[4];

  u16* xb   = (u16*)d_ws;                       // [4096][1024]
  u16* wqkv = xb   + (size_t)NM*NC;             // [3072][1024] (Wq|Wk|Wv rows)
  u16* wpj  = wqkv + (size_t)3*NC*NC;           // [1024][1024] (contiguous after wqkv)
  u16* qb   = wpj  + (size_t)NC*NC;             // [BH][T][D], pre-scaled log2e/8
  u16* kb   = qb   + (size_t)NM*NC;             // [BH][T][D]
  u16* vtb  = kb   + (size_t)NM*NC;             // [BH][D][T]
  u16* yb   = vtb  + (size_t)NM*NC;             // [4096][1024]
  size_t need = ((size_t)NM*NC*5 + (size_t)4*NC*NC) * sizeof(u16);
  if (ws_size < need) return;                   // fail loudly (output stays zero)

  cvt_kernel<<<NM*NC/4/256, 256, 0, stream>>>(x, xb, NM*NC/4);
  cvtw_kernel<<<4*NC*NC/4/256, 256, 0, stream>>>(Wq, Wk, Wv, Wp, wqkv);

  gemm_bt<0><<<dim3(3*NC/128, NM/128), 256, 0, stream>>>(xb, wqkv, NC, 3*NC,
                                                         qb, kb, vtb, nullptr);
  attn_kernel<<<dim3(32, NB*NH), 256, 0, stream>>>(qb, kb, vtb, yb);
  gemm_bt<1><<<dim3(NC/128, NM/128), 256, 0, stream>>>(yb, wpj, NC, NC,
                                                       nullptr, nullptr, nullptr,
                                                       (float*)d_out);
}

// Round 5
// 152.966 us; speedup vs baseline: 1.7782x; 1.1639x over previous
//
#include <hip/hip_runtime.h>
#include <stdint.h>

typedef uint16_t u16;
typedef uint32_t u32;
typedef __attribute__((ext_vector_type(8))) _Float16 f16x8;
typedef __attribute__((ext_vector_type(2))) _Float16 f16x2;
typedef __attribute__((ext_vector_type(4))) float f32x4;

#define NB 2
#define NT 2048
#define NC 1024
#define NH 16
#define ND 64
#define NM (NB*NT)   // 4096 rows of x
#define LOG2E 1.44269504088896340736f

__device__ __forceinline__ u16 f2h(float f) {
  _Float16 h = (_Float16)f;   // RNE
  return __builtin_bit_cast(u16, h);
}

// ---------------- f32 -> f16 convert, 4 elems/thread ----------------
__global__ __launch_bounds__(256) void cvt_kernel(const float* __restrict__ src,
                                                  u16* __restrict__ dst, int n4) {
  int i = blockIdx.x * 256 + threadIdx.x;
  if (i >= n4) return;
  float4 v = ((const float4*)src)[i];
  ushort4 o;
  o.x = f2h(v.x); o.y = f2h(v.y); o.z = f2h(v.z); o.w = f2h(v.w);
  ((ushort4*)dst)[i] = o;
}

// 4 weights -> one contiguous f16 region (Wq|Wk|Wv|Wproj)
__global__ __launch_bounds__(256) void cvtw_kernel(const float* __restrict__ w0,
                                                   const float* __restrict__ w1,
                                                   const float* __restrict__ w2,
                                                   const float* __restrict__ w3,
                                                   u16* __restrict__ dst) {
  int i = blockIdx.x * 256 + threadIdx.x;       // 0 .. 4*NC*NC/4
  int which = i >> 18;                          // NC*NC/4 = 262144
  const float* src = (which == 0) ? w0 : (which == 1) ? w1 : (which == 2) ? w2 : w3;
  int j = i & 262143;
  float4 v = ((const float4*)src)[j];
  ushort4 o;
  o.x = f2h(v.x); o.y = f2h(v.y); o.z = f2h(v.z); o.w = f2h(v.w);
  ((ushort4*)dst)[i] = o;
}

// ---------------- async global->LDS 16B ----------------
__device__ __forceinline__ void gload16(const void* g, void* l) {
  __builtin_amdgcn_global_load_lds(
      (const __attribute__((address_space(1))) void*)g,
      (__attribute__((address_space(3))) void*)l, 16, 0, 0);
}

// ---------------- GEMM, both operands k-major (C[m][n] = sum_k A[m][k]*B[n][k]) ---
// EPI 0: QKV epilogue (scatter q/k [BH][T][D] f16, v transposed [BH][D][T] f16,
//        q *= 0.125*log2(e) so attention works in exp2 domain)
// EPI 1: f32 row-major output
template<int EPI>
__global__ __launch_bounds__(256) void gemm_bt(const u16* __restrict__ A,
                                               const u16* __restrict__ Bw,
                                               int K, int N,
                                               u16* __restrict__ oq, u16* __restrict__ okk,
                                               u16* __restrict__ ovt,
                                               float* __restrict__ of) {
  __shared__ __align__(16) u16 Al[128*64];
  __shared__ __align__(16) u16 Bl[128*64];
  const int tid = threadIdx.x, lane = tid & 63, wid = tid >> 6;
  const int wm = wid >> 1, wn = wid & 1;
  const int m0 = blockIdx.y * 128, n0 = blockIdx.x * 128;
  const int srow = lane >> 3;          // row within an 8-row staging issue
  const int scol = (lane & 7) * 8;     // k-offset (elements) within row

  f32x4 acc[4][4] = {};

  for (int kt = 0; kt < K; kt += 64) {
    #pragma unroll
    for (int pp = 0; pp < 4; ++pp) {
      int r = wid*32 + pp*8;
      gload16(A  + (size_t)(m0 + r + srow)*K + kt + scol, &Al[r*64]);
      gload16(Bw + (size_t)(n0 + r + srow)*K + kt + scol, &Bl[r*64]);
    }
    __syncthreads();
    #pragma unroll
    for (int kk = 0; kk < 2; ++kk) {
      f16x8 af[4], bfr[4];
      #pragma unroll
      for (int mt = 0; mt < 4; ++mt)
        af[mt] = *(const f16x8*)&Al[(wm*64 + mt*16 + (lane&15))*64 + kk*32 + 8*(lane>>4)];
      #pragma unroll
      for (int nt = 0; nt < 4; ++nt)
        bfr[nt] = *(const f16x8*)&Bl[(wn*64 + nt*16 + (lane&15))*64 + kk*32 + 8*(lane>>4)];
      #pragma unroll
      for (int mt = 0; mt < 4; ++mt)
        #pragma unroll
        for (int nt = 0; nt < 4; ++nt)
          acc[mt][nt] = __builtin_amdgcn_mfma_f32_16x16x32_f16(af[mt], bfr[nt], acc[mt][nt], 0, 0, 0);
    }
    __syncthreads();
  }

  if (EPI == 0) {
    #pragma unroll
    for (int nt = 0; nt < 4; ++nt) {
      int n = n0 + wn*64 + nt*16 + (lane & 15);
      int sel = n >> 10;          // 0=q, 1=k, 2=v
      int nn = n & 1023;
      int h = nn >> 6, d = nn & 63;
      float scale = (sel == 0) ? 0.125f*LOG2E : 1.0f;
      #pragma unroll
      for (int mt = 0; mt < 4; ++mt) {
        #pragma unroll
        for (int r = 0; r < 4; ++r) {
          int m = m0 + wm*64 + mt*16 + (lane>>4)*4 + r;
          int b = m >> 11, t = m & (NT-1);
          u16 val = f2h(acc[mt][nt][r] * scale);
          int bh = b*NH + h;
          if (sel == 0)      oq [((size_t)bh*NT + t)*ND + d] = val;
          else if (sel == 1) okk[((size_t)bh*NT + t)*ND + d] = val;
          else               ovt[((size_t)bh*ND + d)*NT + t] = val;
        }
      }
    }
  } else {
    #pragma unroll
    for (int mt = 0; mt < 4; ++mt)
      #pragma unroll
      for (int r = 0; r < 4; ++r) {
        int m = m0 + wm*64 + mt*16 + (lane>>4)*4 + r;
        #pragma unroll
        for (int nt = 0; nt < 4; ++nt) {
          int n = n0 + wn*64 + nt*16 + (lane & 15);
          of[(size_t)m*N + n] = acc[mt][nt][r];
        }
      }
  }
}

// ---------------- flash attention, causal, swapped-QK^T + balance + dbuf ------
// grid: x = B*H (32), y = 32 -> qtile = y ^ h[y>>3], h={0,31,8,23}.
//   Co-CU blocks (id mod 256, stride-256 set) = same x, y in {y0,y0+8,y0+16,y0+24}
//   -> qtiles {a,23-a,24+a,15-a} -> EXACTLY 66 kv-iters per CU (perfect balance).
//   XCD = id%8 = bh%8 -> 4 bh per XCD -> K/V (2MB) resident in 4MB XCD L2.
// K/V double-buffered: stage(kt+1) issued at top of iter, compute(kt) hides the
// latency, ONE barrier per iter (drains the in-flight stage at iter end).
__global__ __launch_bounds__(256) void attn_kernel(const u16* __restrict__ q,
                                                   const u16* __restrict__ k,
                                                   const u16* __restrict__ vt,
                                                   u16* __restrict__ y) {
  __shared__ __align__(16) u16 Kl[2][64*64];
  __shared__ __align__(16) u16 Vl[2][64*64];
  __shared__ __align__(16) u16 Pl[4*16*64];
  const int tid = threadIdx.x, lane = tid & 63, wid = tid >> 6;
  const int g = lane >> 4, qq = lane & 15;
  const int bh = blockIdx.x;
  const int yy = blockIdx.y;
  const int hmap4[4] = {0, 31, 8, 23};
  const int qtile = yy ^ hmap4[yy >> 3];
  const int qs = qtile * 64;
  const u16* qp = q  + (size_t)bh*NT*ND;
  const u16* kp = k  + (size_t)bh*NT*ND;
  const u16* vp = vt + (size_t)bh*ND*NT;
  const int b = bh >> 4, h = bh & 15;
  const int srow = lane >> 3;
  const int scol8 = (lane & 7) ^ (srow & 7);  // pre-swizzled 16B-slot in global source
  u16* pl = &Pl[wid*1024];
  u32* plw = (u32*)pl;

  // Q B-fragment in registers (col q = qs + wid*16 + qq)
  f16x8 aq[2];
  {
    int t = qs + wid*16 + qq;
    #pragma unroll
    for (int c = 0; c < 2; ++c)
      aq[c] = *(const f16x8*)(qp + (size_t)t*ND + c*32 + 8*g);
  }

  f32x4 accO[4] = {};               // O[q-local = g*4+r][d = nt*16+qq]
  float m_run = -1e30f, ssum = 0.f; // per-lane, q = qq (replicated across g)

  const int ntiles = qtile + 1;     // causal: kv tiles 0..qtile

  // prologue: stage kv tile 0 into buf 0
  #pragma unroll
  for (int pp = 0; pp < 2; ++pp) {
    int issue = wid*2 + pp;
    int row = issue*8 + srow;
    gload16(kp + (size_t)row*ND + scol8*8, &Kl[0][issue*512]);
    gload16(vp + (size_t)row*NT + scol8*8, &Vl[0][issue*512]);
  }

  for (int kt = 0; kt < ntiles; ++kt) {
    const int kvs = kt*64;
    const int cur = kt & 1;
    __syncthreads();                // stage(kt) drained (all waves); buf cur^1 free

    if (kt + 1 < ntiles) {          // issue next-tile stage; lands under compute(kt)
      const int kvs2 = kvs + 64;
      #pragma unroll
      for (int pp = 0; pp < 2; ++pp) {
        int issue = wid*2 + pp;
        int row = issue*8 + srow;
        gload16(kp + (size_t)(kvs2 + row)*ND + scol8*8, &Kl[cur^1][issue*512]);
        gload16(vp + (size_t)row*NT + kvs2 + scol8*8, &Vl[cur^1][issue*512]);
      }
    }

    // S^T = K Q^T: rows kv (from K as A), cols q (from Q as B)
    f32x4 sacc[4] = {};             // sacc[nt][r]: kv = kvs+nt*16+g*4+r, q = qs+wid*16+qq
    __builtin_amdgcn_s_setprio(1);
    #pragma unroll
    for (int c = 0; c < 2; ++c) {
      #pragma unroll
      for (int nt = 0; nt < 4; ++nt) {
        int row = nt*16 + qq;
        int col = (c*32 + 8*g) ^ ((row & 7) << 3);
        f16x8 kb = *(const f16x8*)&Kl[cur][row*64 + col];
        sacc[nt] = __builtin_amdgcn_mfma_f32_16x16x32_f16(kb, aq[c], sacc[nt], 0, 0, 0);
      }
    }
    __builtin_amdgcn_s_setprio(0);

    // causal mask (wave-uniform skip: only diagonal tiles mask)
    if (kvs + 63 > qs + wid*16) {
      int qg = qs + wid*16 + qq;
      #pragma unroll
      for (int nt = 0; nt < 4; ++nt)
        #pragma unroll
        for (int r = 0; r < 4; ++r)
          if (kvs + nt*16 + g*4 + r > qg) sacc[nt][r] = -1e30f;
    }

    // lane-local softmax: max/sum over 16 in-lane + 2 shfl (xor 16, 32)
    float mloc = sacc[0][0];
    #pragma unroll
    for (int nt = 0; nt < 4; ++nt)
      #pragma unroll
      for (int r = 0; r < 4; ++r) mloc = fmaxf(mloc, sacc[nt][r]);
    mloc = fmaxf(mloc, __shfl_xor(mloc, 16));
    mloc = fmaxf(mloc, __shfl_xor(mloc, 32));

    const bool defer = __all(mloc <= m_run + 8.f);   // P bounded by 2^8, f16-safe
    float mnew = defer ? m_run : fmaxf(m_run, mloc);

    float p[4][4];
    float ps = 0.f;
    #pragma unroll
    for (int nt = 0; nt < 4; ++nt)
      #pragma unroll
      for (int r = 0; r < 4; ++r) {
        float e = exp2f(sacc[nt][r] - mnew);
        p[nt][r] = e; ps += e;
      }
    ps += __shfl_xor(ps, 16);
    ps += __shfl_xor(ps, 32);

    if (defer) {
      ssum += ps;
    } else {
      float a = exp2f(m_run - mnew);
      ssum = ssum*a + ps;
      m_run = mnew;
      #pragma unroll
      for (int r = 0; r < 4; ++r) {       // broadcast alpha[q=g*4+r] from lane (lane&48)+g*4+r
        float ar = __shfl(a, (lane & 48) + g*4 + r);
        #pragma unroll
        for (int nt = 0; nt < 4; ++nt) accO[nt][r] *= ar;
      }
    }

    // pack P (f16 pairs) -> per-wave LDS [q][kv], 16B-slot XOR swizzle
    #pragma unroll
    for (int nt = 0; nt < 4; ++nt)
      #pragma unroll
      for (int t2 = 0; t2 < 2; ++t2) {
        u32 pk = __builtin_bit_cast(u32,
                   __builtin_amdgcn_cvt_pkrtz(p[nt][2*t2], p[nt][2*t2+1]));
        int kv = nt*16 + g*4 + 2*t2;
        plw[(qq*64 + (kv ^ ((qq & 7) << 3))) >> 1] = pk;
      }

    // O += P V : A = P[q][kv] (LDS, wave-local), B = V^T[d][kv]
    __builtin_amdgcn_s_setprio(1);
    #pragma unroll
    for (int c = 0; c < 2; ++c) {
      f16x8 pa = *(const f16x8*)&pl[qq*64 + ((c*32 + 8*g) ^ ((qq & 7) << 3))];
      #pragma unroll
      for (int nt = 0; nt < 4; ++nt) {
        int vrow = nt*16 + qq;
        int vcol = (c*32 + 8*g) ^ ((vrow & 7) << 3);
        f16x8 vb = *(const f16x8*)&Vl[cur][vrow*64 + vcol];
        accO[nt] = __builtin_amdgcn_mfma_f32_16x16x32_f16(pa, vb, accO[nt], 0, 0, 0);
      }
    }
    __builtin_amdgcn_s_setprio(0);
  }

  // epilogue: y[b][t][h*64+d] = O / ssum, f16
  float inv = 1.0f / ssum;
  #pragma unroll
  for (int r = 0; r < 4; ++r) {
    float invr = __shfl(inv, (lane & 48) + g*4 + r);
    int t = qs + wid*16 + g*4 + r;
    #pragma unroll
    for (int nt = 0; nt < 4; ++nt) {
      int d = nt*16 + qq;
      y[((size_t)(b*NT + t))*NC + h*ND + d] = f2h(accO[nt][r] * invr);
    }
  }
}

// ---------------- launch ----------------
extern "C" void kernel_launch(void* const* d_in, const int* in_sizes, int n_in,
                              void* d_out, int out_size, void* d_ws, size_t ws_size,
                              hipStream_t stream) {
  const float* x  = (const float*)d_in[0];
  const float* Wq = (const float*)d_in[1];
  const float* Wk = (const float*)d_in[2];
  const float* Wv = (const float*)d_in[3];
  const float* Wp = (const float*)d_in[4];

  u16* xb   = (u16*)d_ws;                       // [4096][1024]
  u16* wqkv = xb   + (size_t)NM*NC;             // [3072][1024] (Wq|Wk|Wv rows)
  u16* wpj  = wqkv + (size_t)3*NC*NC;           // [1024][1024] (contiguous after wqkv)
  u16* qb   = wpj  + (size_t)NC*NC;             // [BH][T][D], pre-scaled log2e/8
  u16* kb   = qb   + (size_t)NM*NC;             // [BH][T][D]
  u16* vtb  = kb   + (size_t)NM*NC;             // [BH][D][T]
  u16* yb   = vtb  + (size_t)NM*NC;             // [4096][1024]
  size_t need = ((size_t)NM*NC*5 + (size_t)4*NC*NC) * sizeof(u16);
  if (ws_size < need) return;                   // fail loudly (output stays zero)

  cvt_kernel<<<NM*NC/4/256, 256, 0, stream>>>(x, xb, NM*NC/4);
  cvtw_kernel<<<4*NC*NC/4/256, 256, 0, stream>>>(Wq, Wk, Wv, Wp, wqkv);

  gemm_bt<0><<<dim3(3*NC/128, NM/128), 256, 0, stream>>>(xb, wqkv, NC, 3*NC,
                                                         qb, kb, vtb, nullptr);
  attn_kernel<<<dim3(NB*NH, 32), 256, 0, stream>>>(qb, kb, vtb, yb);
  gemm_bt<1><<<dim3(NC/128, NM/128), 256, 0, stream>>>(yb, wpj, NC, NC,
                                                       nullptr, nullptr, nullptr,
                                                       (float*)d_out);
}

// Round 6
// 138.300 us; speedup vs baseline: 1.9667x; 1.1060x over previous
//
#include <hip/hip_runtime.h>
#include <stdint.h>

typedef uint16_t u16;
typedef uint32_t u32;
typedef __attribute__((ext_vector_type(8))) _Float16 f16x8;
typedef __attribute__((ext_vector_type(4))) float f32x4;

#define NB 2
#define NT 2048
#define NC 1024
#define NH 16
#define ND 64
#define NM (NB*NT)   // 4096 rows of x
#define LOG2E 1.44269504088896340736f

__device__ __forceinline__ u16 f2h(float f) {
  _Float16 h = (_Float16)f;   // RNE
  return __builtin_bit_cast(u16, h);
}

// ---------------- f32 -> f16 convert, 4 elems/thread ----------------
__global__ __launch_bounds__(256) void cvt_kernel(const float* __restrict__ src,
                                                  u16* __restrict__ dst, int n4) {
  int i = blockIdx.x * 256 + threadIdx.x;
  if (i >= n4) return;
  float4 v = ((const float4*)src)[i];
  ushort4 o;
  o.x = f2h(v.x); o.y = f2h(v.y); o.z = f2h(v.z); o.w = f2h(v.w);
  ((ushort4*)dst)[i] = o;
}

// 4 weights -> one contiguous f16 region (Wq|Wk|Wv|Wproj)
__global__ __launch_bounds__(256) void cvtw_kernel(const float* __restrict__ w0,
                                                   const float* __restrict__ w1,
                                                   const float* __restrict__ w2,
                                                   const float* __restrict__ w3,
                                                   u16* __restrict__ dst) {
  int i = blockIdx.x * 256 + threadIdx.x;       // 0 .. 4*NC*NC/4
  int which = i >> 18;                          // NC*NC/4 = 262144
  const float* src = (which == 0) ? w0 : (which == 1) ? w1 : (which == 2) ? w2 : w3;
  int j = i & 262143;
  float4 v = ((const float4*)src)[j];
  ushort4 o;
  o.x = f2h(v.x); o.y = f2h(v.y); o.z = f2h(v.z); o.w = f2h(v.w);
  ((ushort4*)dst)[i] = o;
}

// ---------------- async global->LDS 16B ----------------
__device__ __forceinline__ void gload16(const void* g, void* l) {
  __builtin_amdgcn_global_load_lds(
      (const __attribute__((address_space(1))) void*)g,
      (__attribute__((address_space(3))) void*)l, 16, 0, 0);
}

// ---------------- GEMM, both operands k-major (C[m][n] = sum_k A[m][k]*B[n][k]) ---
// EPI 0: QKV epilogue, LDS re-tiled + coalesced 16B stores:
//        q/k -> [BH][T][D] f16 (q *= 0.125*log2e), v -> [BH][D][T] f16 (transposed)
// EPI 1: f32 row-major output
template<int EPI>
__global__ __launch_bounds__(256) void gemm_bt(const u16* __restrict__ A,
                                               const u16* __restrict__ Bw,
                                               int K, int N,
                                               u16* __restrict__ oq, u16* __restrict__ okk,
                                               u16* __restrict__ ovt,
                                               float* __restrict__ of) {
  __shared__ __align__(16) u16 SH[2*128*64];
  u16* Al = SH;
  u16* Bl = SH + 128*64;
  const int tid = threadIdx.x, lane = tid & 63, wid = tid >> 6;
  const int g = lane >> 4, qq = lane & 15;
  const int wm = wid >> 1, wn = wid & 1;
  const int m0 = blockIdx.y * 128, n0 = blockIdx.x * 128;
  const int srow = lane >> 3;          // row within an 8-row staging issue
  const int scol = (lane & 7) * 8;     // k-offset (elements) within row

  f32x4 acc[4][4] = {};

  for (int kt = 0; kt < K; kt += 64) {
    #pragma unroll
    for (int pp = 0; pp < 4; ++pp) {
      int r = wid*32 + pp*8;
      gload16(A  + (size_t)(m0 + r + srow)*K + kt + scol, &Al[r*64]);
      gload16(Bw + (size_t)(n0 + r + srow)*K + kt + scol, &Bl[r*64]);
    }
    __syncthreads();
    #pragma unroll
    for (int kk = 0; kk < 2; ++kk) {
      f16x8 af[4], bfr[4];
      #pragma unroll
      for (int mt = 0; mt < 4; ++mt)
        af[mt] = *(const f16x8*)&Al[(wm*64 + mt*16 + qq)*64 + kk*32 + 8*g];
      #pragma unroll
      for (int nt = 0; nt < 4; ++nt)
        bfr[nt] = *(const f16x8*)&Bl[(wn*64 + nt*16 + qq)*64 + kk*32 + 8*g];
      #pragma unroll
      for (int mt = 0; mt < 4; ++mt)
        #pragma unroll
        for (int nt = 0; nt < 4; ++nt)
          acc[mt][nt] = __builtin_amdgcn_mfma_f32_16x16x32_f16(af[mt], bfr[nt], acc[mt][nt], 0, 0, 0);
    }
    __syncthreads();    // also makes SH safe for epilogue reuse after last iter
  }

  if (EPI == 0) {
    // per-wave private 64x64 u16 region in SH (no barrier needed)
    u16* reg = SH + wid*4096;
    const int sel = n0 >> 10;                 // block-uniform: 0=q, 1=k, 2=v
    const int h = ((n0 & 1023) >> 6) + wn;    // this wave's head
    const int bq = m0 >> 11;                  // block-uniform batch (m-range never crosses)

    if (sel < 2) {
      // layout [mloc][d], phys_d = d ^ (g<<4)  (conflict-free writes)
      const float scale = (sel == 0) ? 0.125f*LOG2E : 1.0f;
      #pragma unroll
      for (int mt = 0; mt < 4; ++mt)
        #pragma unroll
        for (int r = 0; r < 4; ++r) {
          int mloc = mt*16 + g*4 + r;
          #pragma unroll
          for (int nt = 0; nt < 4; ++nt) {
            int d = nt*16 + qq;
            reg[mloc*64 + (d ^ (g << 4))] = f2h(acc[mt][nt][r] * scale);
          }
        }
      u16* dst = (sel == 0) ? oq : okk;
      const int slot = lane & 7;
      #pragma unroll
      for (int i = 0; i < 8; ++i) {
        int row = i*8 + (lane >> 3);
        int physslot = slot ^ (((row >> 2) & 3) << 1);
        f16x8 vvv = *(const f16x8*)&reg[row*64 + physslot*8];
        int m = m0 + wm*64 + row;
        int t = m & (NT-1);
        *(f16x8*)(dst + (((size_t)(bq*NH + h)*NT + t)*ND) + slot*8) = vvv;
      }
    } else {
      // v: layout [d][t-local], phys_col = mloc ^ ((d&7)<<3); r-paired u32 writes
      #pragma unroll
      for (int nt = 0; nt < 4; ++nt) {
        int d = nt*16 + qq;
        int f = (d & 7) << 3;
        #pragma unroll
        for (int mt = 0; mt < 4; ++mt)
          #pragma unroll
          for (int rp = 0; rp < 2; ++rp) {
            int r = rp*2;
            int mloc = mt*16 + g*4 + r;
            u32 pk = (u32)f2h(acc[mt][nt][r]) | ((u32)f2h(acc[mt][nt][r+1]) << 16);
            *(u32*)&reg[d*64 + (mloc ^ f)] = pk;
          }
      }
      const int slot = lane & 7;
      const int t0 = m0 + wm*64;
      #pragma unroll
      for (int i = 0; i < 8; ++i) {
        int d = i*8 + (lane >> 3);
        int physslot = slot ^ (d & 7);
        f16x8 vvv = *(const f16x8*)&reg[d*64 + physslot*8];
        int t = (t0 & (NT-1)) + slot*8;
        *(f16x8*)(ovt + ((size_t)(bq*NH + h)*ND + d)*NT + t) = vvv;
      }
    }
  } else {
    #pragma unroll
    for (int mt = 0; mt < 4; ++mt)
      #pragma unroll
      for (int r = 0; r < 4; ++r) {
        int m = m0 + wm*64 + mt*16 + g*4 + r;
        #pragma unroll
        for (int nt = 0; nt < 4; ++nt) {
          int n = n0 + wn*64 + nt*16 + qq;
          of[(size_t)m*N + n] = acc[mt][nt][r];
        }
      }
  }
}

// ---------------- flash attention, causal, swapped-QK^T + balance + dbuf ------
// grid: x = B*H (32), y = 32 -> qtile = y ^ h[y>>3], h={0,31,8,23}.
//   Co-CU blocks -> qtiles {a,23-a,24+a,15-a} -> exactly 66 kv-iters per CU.
//   XCD = id%8 = bh%8 -> 4 bh per XCD -> K/V (2MB) resident in 4MB XCD L2.
__global__ __launch_bounds__(256) void attn_kernel(const u16* __restrict__ q,
                                                   const u16* __restrict__ k,
                                                   const u16* __restrict__ vt,
                                                   u16* __restrict__ y) {
  __shared__ __align__(16) u16 Kl[2][64*64];
  __shared__ __align__(16) u16 Vl[2][64*64];
  __shared__ __align__(16) u16 Pl[4*16*64];
  const int tid = threadIdx.x, lane = tid & 63, wid = tid >> 6;
  const int g = lane >> 4, qq = lane & 15;
  const int bh = blockIdx.x;
  const int yy = blockIdx.y;
  const int hmap4[4] = {0, 31, 8, 23};
  const int qtile = yy ^ hmap4[yy >> 3];
  const int qs = qtile * 64;
  const u16* qp = q  + (size_t)bh*NT*ND;
  const u16* kp = k  + (size_t)bh*NT*ND;
  const u16* vp = vt + (size_t)bh*ND*NT;
  const int b = bh >> 4, h = bh & 15;
  const int srow = lane >> 3;
  const int scol8 = (lane & 7) ^ (srow & 7);  // pre-swizzled 16B-slot in global source
  u16* pl = &Pl[wid*1024];
  u32* plw = (u32*)pl;

  // Q B-fragment in registers (col q = qs + wid*16 + qq)
  f16x8 aq[2];
  {
    int t = qs + wid*16 + qq;
    #pragma unroll
    for (int c = 0; c < 2; ++c)
      aq[c] = *(const f16x8*)(qp + (size_t)t*ND + c*32 + 8*g);
  }

  f32x4 accO[4] = {};               // O[q-local = g*4+r][d = nt*16+qq]
  float m_run = -1e30f, ssum = 0.f; // per-lane, q = qq (replicated across g)

  const int ntiles = qtile + 1;     // causal: kv tiles 0..qtile

  // prologue: stage kv tile 0 into buf 0
  #pragma unroll
  for (int pp = 0; pp < 2; ++pp) {
    int issue = wid*2 + pp;
    int row = issue*8 + srow;
    gload16(kp + (size_t)row*ND + scol8*8, &Kl[0][issue*512]);
    gload16(vp + (size_t)row*NT + scol8*8, &Vl[0][issue*512]);
  }

  for (int kt = 0; kt < ntiles; ++kt) {
    const int kvs = kt*64;
    const int cur = kt & 1;
    __syncthreads();                // stage(kt) drained (all waves); buf cur^1 free

    if (kt + 1 < ntiles) {          // issue next-tile stage; lands under compute(kt)
      const int kvs2 = kvs + 64;
      #pragma unroll
      for (int pp = 0; pp < 2; ++pp) {
        int issue = wid*2 + pp;
        int row = issue*8 + srow;
        gload16(kp + (size_t)(kvs2 + row)*ND + scol8*8, &Kl[cur^1][issue*512]);
        gload16(vp + (size_t)row*NT + kvs2 + scol8*8, &Vl[cur^1][issue*512]);
      }
    }

    // S^T = K Q^T: rows kv (from K as A), cols q (from Q as B)
    f32x4 sacc[4] = {};             // sacc[nt][r]: kv = kvs+nt*16+g*4+r, q = qs+wid*16+qq
    __builtin_amdgcn_s_setprio(1);
    #pragma unroll
    for (int c = 0; c < 2; ++c) {
      #pragma unroll
      for (int nt = 0; nt < 4; ++nt) {
        int row = nt*16 + qq;
        int col = (c*32 + 8*g) ^ ((row & 7) << 3);
        f16x8 kb = *(const f16x8*)&Kl[cur][row*64 + col];
        sacc[nt] = __builtin_amdgcn_mfma_f32_16x16x32_f16(kb, aq[c], sacc[nt], 0, 0, 0);
      }
    }
    __builtin_amdgcn_s_setprio(0);

    // causal mask (wave-uniform skip: only diagonal tiles mask)
    if (kvs + 63 > qs + wid*16) {
      int qg = qs + wid*16 + qq;
      #pragma unroll
      for (int nt = 0; nt < 4; ++nt)
        #pragma unroll
        for (int r = 0; r < 4; ++r)
          if (kvs + nt*16 + g*4 + r > qg) sacc[nt][r] = -1e30f;
    }

    // lane-local softmax: max/sum over 16 in-lane + 2 shfl (xor 16, 32)
    float mloc = sacc[0][0];
    #pragma unroll
    for (int nt = 0; nt < 4; ++nt)
      #pragma unroll
      for (int r = 0; r < 4; ++r) mloc = fmaxf(mloc, sacc[nt][r]);
    mloc = fmaxf(mloc, __shfl_xor(mloc, 16));
    mloc = fmaxf(mloc, __shfl_xor(mloc, 32));

    const bool defer = __all(mloc <= m_run + 8.f);   // P bounded by 2^8, f16-safe
    float mnew = defer ? m_run : fmaxf(m_run, mloc);

    float p[4][4];
    float ps = 0.f;
    #pragma unroll
    for (int nt = 0; nt < 4; ++nt)
      #pragma unroll
      for (int r = 0; r < 4; ++r) {
        float e = exp2f(sacc[nt][r] - mnew);
        p[nt][r] = e; ps += e;
      }
    ps += __shfl_xor(ps, 16);
    ps += __shfl_xor(ps, 32);

    if (defer) {
      ssum += ps;
    } else {
      float a = exp2f(m_run - mnew);
      ssum = ssum*a + ps;
      m_run = mnew;
      #pragma unroll
      for (int r = 0; r < 4; ++r) {       // broadcast alpha[q=g*4+r] from lane (lane&48)+g*4+r
        float ar = __shfl(a, (lane & 48) + g*4 + r);
        #pragma unroll
        for (int nt = 0; nt < 4; ++nt) accO[nt][r] *= ar;
      }
    }

    // pack P (f16 pairs) -> per-wave LDS [q][kv], 16B-slot XOR swizzle
    #pragma unroll
    for (int nt = 0; nt < 4; ++nt)
      #pragma unroll
      for (int t2 = 0; t2 < 2; ++t2) {
        u32 pk = __builtin_bit_cast(u32,
                   __builtin_amdgcn_cvt_pkrtz(p[nt][2*t2], p[nt][2*t2+1]));
        int kv = nt*16 + g*4 + 2*t2;
        plw[(qq*64 + (kv ^ ((qq & 7) << 3))) >> 1] = pk;
      }

    // O += P V : A = P[q][kv] (LDS, wave-local), B = V^T[d][kv]
    __builtin_amdgcn_s_setprio(1);
    #pragma unroll
    for (int c = 0; c < 2; ++c) {
      f16x8 pa = *(const f16x8*)&pl[qq*64 + ((c*32 + 8*g) ^ ((qq & 7) << 3))];
      #pragma unroll
      for (int nt = 0; nt < 4; ++nt) {
        int vrow = nt*16 + qq;
        int vcol = (c*32 + 8*g) ^ ((vrow & 7) << 3);
        f16x8 vb = *(const f16x8*)&Vl[cur][vrow*64 + vcol];
        accO[nt] = __builtin_amdgcn_mfma_f32_16x16x32_f16(pa, vb, accO[nt], 0, 0, 0);
      }
    }
    __builtin_amdgcn_s_setprio(0);
  }

  // epilogue: y[b][t][h*64+d] = O / ssum, f16
  float inv = 1.0f / ssum;
  #pragma unroll
  for (int r = 0; r < 4; ++r) {
    float invr = __shfl(inv, (lane & 48) + g*4 + r);
    int t = qs + wid*16 + g*4 + r;
    #pragma unroll
    for (int nt = 0; nt < 4; ++nt) {
      int d = nt*16 + qq;
      y[((size_t)(b*NT + t))*NC + h*ND + d] = f2h(accO[nt][r] * invr);
    }
  }
}

// ---------------- launch ----------------
extern "C" void kernel_launch(void* const* d_in, const int* in_sizes, int n_in,
                              void* d_out, int out_size, void* d_ws, size_t ws_size,
                              hipStream_t stream) {
  const float* x  = (const float*)d_in[0];
  const float* Wq = (const float*)d_in[1];
  const float* Wk = (const float*)d_in[2];
  const float* Wv = (const float*)d_in[3];
  const float* Wp = (const float*)d_in[4];

  u16* xb   = (u16*)d_ws;                       // [4096][1024]
  u16* wqkv = xb   + (size_t)NM*NC;             // [3072][1024] (Wq|Wk|Wv rows)
  u16* wpj  = wqkv + (size_t)3*NC*NC;           // [1024][1024] (contiguous after wqkv)
  u16* qb   = wpj  + (size_t)NC*NC;             // [BH][T][D], pre-scaled log2e/8
  u16* kb   = qb   + (size_t)NM*NC;             // [BH][T][D]
  u16* vtb  = kb   + (size_t)NM*NC;             // [BH][D][T]
  u16* yb   = vtb  + (size_t)NM*NC;             // [4096][1024]
  size_t need = ((size_t)NM*NC*5 + (size_t)4*NC*NC) * sizeof(u16);
  if (ws_size < need) return;                   // fail loudly (output stays zero)

  cvt_kernel<<<NM*NC/4/256, 256, 0, stream>>>(x, xb, NM*NC/4);
  cvtw_kernel<<<4*NC*NC/4/256, 256, 0, stream>>>(Wq, Wk, Wv, Wp, wqkv);

  gemm_bt<0><<<dim3(3*NC/128, NM/128), 256, 0, stream>>>(xb, wqkv, NC, 3*NC,
                                                         qb, kb, vtb, nullptr);
  attn_kernel<<<dim3(NB*NH, 32), 256, 0, stream>>>(qb, kb, vtb, yb);
  gemm_bt<1><<<dim3(NC/128, NM/128), 256, 0, stream>>>(yb, wpj, NC, NC,
                                                       nullptr, nullptr, nullptr,
                                                       (float*)d_out);
}